// Round 12
// baseline (330.561 us; speedup 1.0000x reference)
//
#include <hip/hip_runtime.h>

#define H 512
#define W 512
#define HW (H * W)
#define BATCH 32
#define KS 5
#define NBH 4              // batches per block
#define NSTEP (KS * NBH)   // 20 pipelined steps per block
#define PD 3               // f-load lookahead (steps)

typedef float nf4 __attribute__((ext_vector_type(4)));

// One output row r, NBH batches per block. Loop nest is TAP-ROW-outer /
// batch-inner, so only ONE K tap-row (5 x float4, double-buffered = 40 VGPR)
// is live at a time -- small enough that the compiler keeps it in real VGPRs
// (round-2 version needed all 25 taps = 100 VGPR live and the compiler
// demoted them; VGPR_Count=104, occupancy 16%, 60us latency-bound).
// acc[NBH][4]=16 regs persists across tap-rows; the f-center value for the
// epilogue is RE-LOADED (L2 hit) with a 2-step ring instead of held 16 steps.
// ~120 VGPR -> 4 waves/EU; grid 4096 blocks = 8192 waves = 32/CU available.
// NO LDS, NO BARRIERS.
__global__ __launch_bounds__(128, 3) void op2d_kernel(
    const float* __restrict__ f,   // (B,H,W)
    const float* __restrict__ K,   // (5,5,H,W)
    const float* __restrict__ dt,  // (B,)
    float* __restrict__ out)       // (B,H,W)
{
    const int tid = threadIdx.x;             // 0..127
    const int w0  = tid * 4;                 // 0..508
    const int bx  = blockIdx.x;
    // XCD-contiguous row bands: rows r and r+1 are 8 block-IDs apart (same
    // XCD), y-groups of the same row are 512 apart (0 mod 8, same XCD) ->
    // K rows and f halo rows are L2-local to one XCD.
    const int r   = (bx & 7) * 64 + (bx >> 3);
    const int b0  = blockIdx.y * NBH;

    const bool wl = (w0 >= 4);
    const bool wr = (w0 <= 504);

    // Clamped source-row offsets for the 5 tap-rows (block-uniform -> SGPR).
    int rowoff[KS];
    bool inb[KS];
#pragma unroll
    for (int i = 0; i < KS; ++i) {
        const int gr = r + i - 2;
        inb[i] = (gr >= 0) && (gr < H);
        rowoff[i] = (gr < 0 ? 0 : (gr >= H ? H - 1 : gr)) * W;
    }

    // f stream: step s -> tap-row i = s/NBH, batch bi = s%NBH.
    // A step copies its slot out, then refills the same slot for step s+PD
    // -> each load has PD steps to complete.
    nf4 rbuf[PD][3];
#define FISSUE(s)                                                            \
    {                                                                        \
        const float* fb = f + (size_t)(b0 + (s) % NBH) * HW                  \
                            + rowoff[(s) / NBH] + w0;                        \
        rbuf[(s) % PD][0] = wl ? *(const nf4*)(fb - 4) : (nf4)0.f;           \
        rbuf[(s) % PD][1] =      *(const nf4*)(fb);                          \
        rbuf[(s) % PD][2] = wr ? *(const nf4*)(fb + 4) : (nf4)0.f;           \
    }

    // f prologue first (earliest-needed data at the head of the VMEM FIFO).
#pragma unroll
    for (int s = 0; s < PD; ++s) FISSUE(s);

    // K tap-row 0 into buffer 0. OOB tap-rows contribute zero (zero-padding):
    // zero the K registers; the clamped f row address reads garbage * 0 = 0.
    nf4 Kb[2][KS];
#pragma unroll
    for (int j = 0; j < KS; ++j)
        Kb[0][j] = inb[0] ? *(const nf4*)(K + ((size_t)j * H + r) * W + w0)
                          : (nf4)0.f;

    float dtb[NBH];
#pragma unroll
    for (int bi = 0; bi < NBH; ++bi) dtb[bi] = dt[b0 + bi];  // uniform -> s_load

    float acc[NBH][4] = {};   // df accumulators, live across all tap-rows
    nf4 fcr[2];               // f-center reload ring (2-step lookahead)

#pragma unroll
    for (int i = 0; i < KS; ++i) {
#pragma unroll
        for (int bi = 0; bi < NBH; ++bi) {
            const int s = i * NBH + bi;

            // consume this step's f window, then refill the slot PD ahead
            const nf4 ra = rbuf[s % PD][0];
            const nf4 rb = rbuf[s % PD][1];
            const nf4 rc = rbuf[s % PD][2];
            if (s + PD < NSTEP) FISSUE(s + PD);

            // Front-load ALL of next tap-row's K at batch-step 0:
            // 4 batch-steps (~160+ cyc/wave, ~640 cyc wall at 4 waves/EU)
            // of cover before first use.
            if (bi == 0 && i + 1 < KS) {
#pragma unroll
                for (int j = 0; j < KS; ++j)
                    Kb[(i + 1) & 1][j] = inb[i + 1]
                        ? *(const nf4*)(K + ((size_t)((i + 1) * KS + j) * H + r) * W + w0)
                        : (nf4)0.f;
            }

            // f-center reloads for the first 2 epilogue batches (2-step cover).
            if (i == KS - 2 && bi >= NBH - 2) {
                const int bt = bi - (NBH - 2);
                fcr[bt & 1] = *(const nf4*)(f + (size_t)(b0 + bt) * HW
                                              + (size_t)r * W + w0);
            }

            const float buf[12] = { ra.x, ra.y, ra.z, ra.w,
                                    rb.x, rb.y, rb.z, rb.w,
                                    rc.x, rc.y, rc.z, rc.w };

            // 20 FMAs, 4 independent chains (8cy issue > 4cy latency).
#pragma unroll
            for (int j = 0; j < KS; ++j) {
                const nf4 kv = Kb[i & 1][j];
                acc[bi][0] += kv.x * buf[j + 2];
                acc[bi][1] += kv.y * buf[j + 3];
                acc[bi][2] += kv.z * buf[j + 4];
                acc[bi][3] += kv.w * buf[j + 5];
            }

            // batch bi complete after its last tap-row: store immediately,
            // and issue the f-center reload for batch bi+2 into the ring.
            if (i == KS - 1) {
                const nf4 fc = fcr[bi & 1];
                if (bi + 2 < NBH)
                    fcr[bi & 1] = *(const nf4*)(f + (size_t)(b0 + bi + 2) * HW
                                                  + (size_t)r * W + w0);
                nf4 o;
                o.x = fmaxf(fc.x + acc[bi][0] * dtb[bi], 0.f);
                o.y = fmaxf(fc.y + acc[bi][1] * dtb[bi], 0.f);
                o.z = fmaxf(fc.z + acc[bi][2] * dtb[bi], 0.f);
                o.w = fmaxf(fc.w + acc[bi][3] * dtb[bi], 0.f);
                __builtin_nontemporal_store(o,
                    (nf4*)(out + ((size_t)(b0 + bi) * H + r) * W + w0));
            }
        }
    }
#undef FISSUE
}

extern "C" void kernel_launch(void* const* d_in, const int* in_sizes, int n_in,
                              void* d_out, int out_size, void* d_ws, size_t ws_size,
                              hipStream_t stream) {
    const float* f  = (const float*)d_in[0];   // (32,512,512)
    const float* K  = (const float*)d_in[1];   // (5,5,512,512)
    const float* dt = (const float*)d_in[2];   // (32,)
    float* out = (float*)d_out;

    dim3 block(128);
    dim3 grid(H, BATCH / NBH);   // 512 rows x 8 batch-groups = 4096 blocks
    op2d_kernel<<<grid, block, 0, stream>>>(f, K, dt, out);
}

// Round 13
// 221.030 us; speedup vs baseline: 1.4955x; 1.4955x over previous
//
#include <hip/hip_runtime.h>

#define H 512
#define W 512
#define HW (H * W)
#define BATCH 32
#define KS 5
#define NBH 4              // batches per block
#define NSTEP (KS * NBH)   // 20 pipelined steps per block
#define PD 3               // f-load lookahead (steps)

typedef float nf4 __attribute__((ext_vector_type(4)));

// One output row r, NBH batches per block; tap-row-outer / batch-inner so only
// ONE K tap-row (5 x float4, double-buffered = 40 VGPR) is live at a time.
// Persistent state: acc[NBH][4] + 2-slot f-center ring. ~130 live VGPRs.
//
// LAUNCH BOUNDS: (128,2) ONLY. Round-12 measured (128,3) => allocator clamped
// to 84 VGPRs (6-wave/EU budget), ~46 regs spilled in the unrolled loop:
// WRITE_SIZE 32MB->500MB, FETCH 39->389MB, VALUBusy 0.1%, 331us. The bound
// CAUSED the spill (G1: bound only to the occupancy you need). (128,2) is the
// proven no-spill config (round 2: WRITE exactly 32MB).
// NO LDS, NO BARRIERS.
__global__ __launch_bounds__(128, 2) void op2d_kernel(
    const float* __restrict__ f,   // (B,H,W)
    const float* __restrict__ K,   // (5,5,H,W)
    const float* __restrict__ dt,  // (B,)
    float* __restrict__ out)       // (B,H,W)
{
    const int tid = threadIdx.x;             // 0..127
    const int w0  = tid * 4;                 // 0..508
    const int bx  = blockIdx.x;
    // XCD-contiguous row bands: rows r and r+1 are 8 block-IDs apart (same
    // XCD), y-groups of the same row are 512 apart (0 mod 8, same XCD) ->
    // K rows and f halo rows are L2-local to one XCD.
    const int r   = (bx & 7) * 64 + (bx >> 3);
    const int b0  = blockIdx.y * NBH;

    const bool wl = (w0 >= 4);
    const bool wr = (w0 <= 504);

    // Clamped source-row offsets for the 5 tap-rows (block-uniform -> SGPR).
    int rowoff[KS];
    bool inb[KS];
#pragma unroll
    for (int i = 0; i < KS; ++i) {
        const int gr = r + i - 2;
        inb[i] = (gr >= 0) && (gr < H);
        rowoff[i] = (gr < 0 ? 0 : (gr >= H ? H - 1 : gr)) * W;
    }

    // f stream: step s -> tap-row i = s/NBH, batch bi = s%NBH.
    // A step copies its slot out, then refills the same slot for step s+PD
    // -> each load has PD steps to complete.
    nf4 rbuf[PD][3];
#define FISSUE(s)                                                            \
    {                                                                        \
        const float* fb = f + (size_t)(b0 + (s) % NBH) * HW                  \
                            + rowoff[(s) / NBH] + w0;                        \
        rbuf[(s) % PD][0] = wl ? *(const nf4*)(fb - 4) : (nf4)0.f;           \
        rbuf[(s) % PD][1] =      *(const nf4*)(fb);                          \
        rbuf[(s) % PD][2] = wr ? *(const nf4*)(fb + 4) : (nf4)0.f;           \
    }

    // f prologue first (earliest-needed data at the head of the VMEM FIFO).
#pragma unroll
    for (int s = 0; s < PD; ++s) FISSUE(s);

    // K tap-row 0 into buffer 0. OOB tap-rows contribute zero (zero-padding):
    // zero the K registers; the clamped f row address reads garbage * 0 = 0.
    nf4 Kb[2][KS];
#pragma unroll
    for (int j = 0; j < KS; ++j)
        Kb[0][j] = inb[0] ? *(const nf4*)(K + ((size_t)j * H + r) * W + w0)
                          : (nf4)0.f;

    float dtb[NBH];
#pragma unroll
    for (int bi = 0; bi < NBH; ++bi) dtb[bi] = dt[b0 + bi];  // uniform -> s_load

    float acc[NBH][4] = {};   // df accumulators, live across all tap-rows
    nf4 fcr[2];               // f-center reload ring (2-step lookahead)

#pragma unroll
    for (int i = 0; i < KS; ++i) {
#pragma unroll
        for (int bi = 0; bi < NBH; ++bi) {
            const int s = i * NBH + bi;

            // consume this step's f window, then refill the slot PD ahead
            const nf4 ra = rbuf[s % PD][0];
            const nf4 rb = rbuf[s % PD][1];
            const nf4 rc = rbuf[s % PD][2];
            if (s + PD < NSTEP) FISSUE(s + PD);

            // Front-load ALL of next tap-row's K at batch-step 0:
            // 4 batch-steps of cover before first use.
            if (bi == 0 && i + 1 < KS) {
#pragma unroll
                for (int j = 0; j < KS; ++j)
                    Kb[(i + 1) & 1][j] = inb[i + 1]
                        ? *(const nf4*)(K + ((size_t)((i + 1) * KS + j) * H + r) * W + w0)
                        : (nf4)0.f;
            }

            // f-center reloads for the first 2 epilogue batches (2-step cover).
            if (i == KS - 2 && bi >= NBH - 2) {
                const int bt = bi - (NBH - 2);
                fcr[bt & 1] = *(const nf4*)(f + (size_t)(b0 + bt) * HW
                                              + (size_t)r * W + w0);
            }

            const float buf[12] = { ra.x, ra.y, ra.z, ra.w,
                                    rb.x, rb.y, rb.z, rb.w,
                                    rc.x, rc.y, rc.z, rc.w };

            // 20 FMAs, 4 independent chains (8cy issue > 4cy latency).
#pragma unroll
            for (int j = 0; j < KS; ++j) {
                const nf4 kv = Kb[i & 1][j];
                acc[bi][0] += kv.x * buf[j + 2];
                acc[bi][1] += kv.y * buf[j + 3];
                acc[bi][2] += kv.z * buf[j + 4];
                acc[bi][3] += kv.w * buf[j + 5];
            }

            // batch bi complete after its last tap-row: store immediately,
            // and issue the f-center reload for batch bi+2 into the ring.
            if (i == KS - 1) {
                const nf4 fc = fcr[bi & 1];
                if (bi + 2 < NBH)
                    fcr[bi & 1] = *(const nf4*)(f + (size_t)(b0 + bi + 2) * HW
                                                  + (size_t)r * W + w0);
                nf4 o;
                o.x = fmaxf(fc.x + acc[bi][0] * dtb[bi], 0.f);
                o.y = fmaxf(fc.y + acc[bi][1] * dtb[bi], 0.f);
                o.z = fmaxf(fc.z + acc[bi][2] * dtb[bi], 0.f);
                o.w = fmaxf(fc.w + acc[bi][3] * dtb[bi], 0.f);
                __builtin_nontemporal_store(o,
                    (nf4*)(out + ((size_t)(b0 + bi) * H + r) * W + w0));
            }
        }
    }
#undef FISSUE
}

extern "C" void kernel_launch(void* const* d_in, const int* in_sizes, int n_in,
                              void* d_out, int out_size, void* d_ws, size_t ws_size,
                              hipStream_t stream) {
    const float* f  = (const float*)d_in[0];   // (32,512,512)
    const float* K  = (const float*)d_in[1];   // (5,5,512,512)
    const float* dt = (const float*)d_in[2];   // (32,)
    float* out = (float*)d_out;

    dim3 block(128);
    dim3 grid(H, BATCH / NBH);   // 512 rows x 8 batch-groups = 4096 blocks
    op2d_kernel<<<grid, block, 0, stream>>>(f, K, dt, out);
}

// Round 16
// 217.516 us; speedup vs baseline: 1.5197x; 1.0162x over previous
//
#include <hip/hip_runtime.h>

#define H 512
#define W 512
#define HW (H * W)
#define BATCH 32
#define KS 5
#define NBH 4              // batches per block
#define NSTEP (KS * NBH)   // 20 pipelined steps per block
#define PD 3               // f-load lookahead (steps)

typedef float nf4 __attribute__((ext_vector_type(4)));

// One output row r, NBH batches per block; tap-row-outer / batch-inner.
// Live state by construction: rbuf 36 + Kb 40 + acc 16 + fcr 8 + addr ~40.
//
// REGISTER BUDGET (measured, rounds 12/13): __launch_bounds__(128,N) budgets
// 512/(2N) VGPRs on this backend -- (128,3)->84, (128,2)->128 -- and the
// design's scheduler-inflated demand (~230, from cross-step load hoisting
// under full unroll) spilled ~100 regs -> 226MB scratch writes, 143-331us.
// Fix: amdgpu_waves_per_eu(2,2) sets the budget to 512/2=256 directly and
// removes the allocator's occupancy ambition; sched_barrier(0) per step
// fences cross-step hoisting so liveness tracks the source pipeline (~150).
// NO LDS, NO BARRIERS (sched_barrier is compile-time only).
__global__ __launch_bounds__(128)
__attribute__((amdgpu_waves_per_eu(2, 2)))
void op2d_kernel(
    const float* __restrict__ f,   // (B,H,W)
    const float* __restrict__ K,   // (5,5,H,W)
    const float* __restrict__ dt,  // (B,)
    float* __restrict__ out)       // (B,H,W)
{
    const int tid = threadIdx.x;             // 0..127
    const int w0  = tid * 4;                 // 0..508
    const int bx  = blockIdx.x;
    // XCD-contiguous row bands: rows r and r+1 are 8 block-IDs apart (same
    // XCD), y-groups of the same row are 512 apart (0 mod 8, same XCD) ->
    // K rows and f halo rows are L2-local to one XCD.
    const int r   = (bx & 7) * 64 + (bx >> 3);
    const int b0  = blockIdx.y * NBH;

    const bool wl = (w0 >= 4);
    const bool wr = (w0 <= 504);

    // Clamped source-row offsets for the 5 tap-rows (block-uniform -> SGPR).
    int rowoff[KS];
    bool inb[KS];
#pragma unroll
    for (int i = 0; i < KS; ++i) {
        const int gr = r + i - 2;
        inb[i] = (gr >= 0) && (gr < H);
        rowoff[i] = (gr < 0 ? 0 : (gr >= H ? H - 1 : gr)) * W;
    }

    // f stream: step s -> tap-row i = s/NBH, batch bi = s%NBH.
    // A step copies its slot out, then refills the same slot for step s+PD
    // -> each load has PD steps (~3 fenced step-bodies) to complete.
    nf4 rbuf[PD][3];
#define FISSUE(s)                                                            \
    {                                                                        \
        const float* fb = f + (size_t)(b0 + (s) % NBH) * HW                  \
                            + rowoff[(s) / NBH] + w0;                        \
        rbuf[(s) % PD][0] = wl ? *(const nf4*)(fb - 4) : (nf4)0.f;           \
        rbuf[(s) % PD][1] =      *(const nf4*)(fb);                          \
        rbuf[(s) % PD][2] = wr ? *(const nf4*)(fb + 4) : (nf4)0.f;           \
    }

    // f prologue first (earliest-needed data at the head of the VMEM FIFO).
#pragma unroll
    for (int s = 0; s < PD; ++s) FISSUE(s);

    // K tap-row 0 into buffer 0. OOB tap-rows contribute zero (zero-padding):
    // zero the K registers; the clamped f row address reads garbage * 0 = 0.
    nf4 Kb[2][KS];
#pragma unroll
    for (int j = 0; j < KS; ++j)
        Kb[0][j] = inb[0] ? *(const nf4*)(K + ((size_t)j * H + r) * W + w0)
                          : (nf4)0.f;

    float dtb[NBH];
#pragma unroll
    for (int bi = 0; bi < NBH; ++bi) dtb[bi] = dt[b0 + bi];  // uniform -> s_load

    float acc[NBH][4] = {};   // df accumulators, live across all tap-rows
    nf4 fcr[2];               // f-center reload ring (2-step lookahead)

#pragma unroll
    for (int i = 0; i < KS; ++i) {
#pragma unroll
        for (int bi = 0; bi < NBH; ++bi) {
            const int s = i * NBH + bi;

            // consume this step's f window, then refill the slot PD ahead
            const nf4 ra = rbuf[s % PD][0];
            const nf4 rb = rbuf[s % PD][1];
            const nf4 rc = rbuf[s % PD][2];
            if (s + PD < NSTEP) FISSUE(s + PD);

            // Front-load ALL of next tap-row's K at batch-step 0:
            // 4 fenced batch-steps of cover before first use.
            if (bi == 0 && i + 1 < KS) {
#pragma unroll
                for (int j = 0; j < KS; ++j)
                    Kb[(i + 1) & 1][j] = inb[i + 1]
                        ? *(const nf4*)(K + ((size_t)((i + 1) * KS + j) * H + r) * W + w0)
                        : (nf4)0.f;
            }

            // f-center reloads for the first 2 epilogue batches (2-step cover).
            if (i == KS - 2 && bi >= NBH - 2) {
                const int bt = bi - (NBH - 2);
                fcr[bt & 1] = *(const nf4*)(f + (size_t)(b0 + bt) * HW
                                              + (size_t)r * W + w0);
            }

            const float buf[12] = { ra.x, ra.y, ra.z, ra.w,
                                    rb.x, rb.y, rb.z, rb.w,
                                    rc.x, rc.y, rc.z, rc.w };

            // 20 FMAs, 4 independent chains (8cy issue > 4cy latency).
#pragma unroll
            for (int j = 0; j < KS; ++j) {
                const nf4 kv = Kb[i & 1][j];
                acc[bi][0] += kv.x * buf[j + 2];
                acc[bi][1] += kv.y * buf[j + 3];
                acc[bi][2] += kv.z * buf[j + 4];
                acc[bi][3] += kv.w * buf[j + 5];
            }

            // batch bi complete after its last tap-row: store immediately,
            // and issue the f-center reload for batch bi+2 into the ring.
            if (i == KS - 1) {
                const nf4 fc = fcr[bi & 1];
                if (bi + 2 < NBH)
                    fcr[bi & 1] = *(const nf4*)(f + (size_t)(b0 + bi + 2) * HW
                                                  + (size_t)r * W + w0);
                nf4 o;
                o.x = fmaxf(fc.x + acc[bi][0] * dtb[bi], 0.f);
                o.y = fmaxf(fc.y + acc[bi][1] * dtb[bi], 0.f);
                o.z = fmaxf(fc.z + acc[bi][2] * dtb[bi], 0.f);
                o.w = fmaxf(fc.w + acc[bi][3] * dtb[bi], 0.f);
                __builtin_nontemporal_store(o,
                    (nf4*)(out + ((size_t)(b0 + bi) * H + r) * W + w0));
            }

            // Fence: no instruction (esp. loads) may migrate across steps.
            // This caps scheduler-inflated liveness at the source pipeline.
            __builtin_amdgcn_sched_barrier(0);
        }
    }
#undef FISSUE
}

extern "C" void kernel_launch(void* const* d_in, const int* in_sizes, int n_in,
                              void* d_out, int out_size, void* d_ws, size_t ws_size,
                              hipStream_t stream) {
    const float* f  = (const float*)d_in[0];   // (32,512,512)
    const float* K  = (const float*)d_in[1];   // (5,5,512,512)
    const float* dt = (const float*)d_in[2];   // (32,)
    float* out = (float*)d_out;

    dim3 block(128);
    dim3 grid(H, BATCH / NBH);   // 512 rows x 8 batch-groups = 4096 blocks
    op2d_kernel<<<grid, block, 0, stream>>>(f, K, dt, out);
}